// Round 9
// baseline (381.893 us; speedup 1.0000x reference)
//
#include <hip/hip_runtime.h>
#include <hip/hip_bf16.h>
#include <math.h>

// GanDTI forward. B=4096, N_ATOMS=50, FEAT=40, GNN_DEPTH=3, MLP_DEPTH=2.
//
// k_main: 12288 blocks x 128 thr, heterogeneous (1:2 interleave for CU mixing):
//   blk%3==0 -> GNN job gid=blk/3 (4096): one sample, TWO waves (100 active
//               lanes, 5 rows x 4 cols tile), comp/h in LDS 17.6KB, Wg/A global.
//   else     -> stream job sid (8192): 4 samples x 128-k chunk of
//               partial a256 = (A69@W1+b1) @ W2; a69 row-dots in registers ->
//               LDS [4][64] sample-major; W2 L2-resident.
//   Rationale: stream is HBM-bound, GNN is VALU/LDS-bound -> co-residency
//   overlaps them instead of serializing two kernels.
// k_tail (UNCHANGED round-8 control): 512 blocks x 256 thr, 8 samples;
//   wave-specialized p256 / a256-reduce, then p40/attention/MLP.

#define BATCH 4096
#define SC 44   // comp/h row stride in GNN part

// ===================== k_main =====================
__global__ __launch_bounds__(128) void k_main(
    const int* __restrict__ atoms, const float* __restrict__ A,
    const float* __restrict__ A69, const float* __restrict__ emb,
    const float* __restrict__ Wg, const float* __restrict__ bg,
    const float* __restrict__ W1, const float* __restrict__ b1,
    const float* __restrict__ W2,
    float* __restrict__ ws_cv, float* __restrict__ ws_part)
{
    __shared__ float sm[4400];   // GNN: comp[50*44]+h[50*44]; stream: a69s[256]
    const int tid = threadIdx.x;
    const int blk = blockIdx.x;

    if (blk % 3 != 0) {
        // ================= stream: 4 samples x 128-k chunk =================
        const int sid = blk - blk / 3 - 1;          // 0..8191
        const int kc = sid & 7, sg = sid >> 3;
        const int s0 = sg * 4, k0 = kc * 128;
        const int lane = tid & 63, wv = tid >> 6;
        const int c0 = lane * 4;
        float* a69s = sm;                            // [4][64] sample-major

        float w1r[30];
        #pragma unroll
        for (int k = 0; k < 15; ++k) {
            float2 t = ((const float2*)W1)[k];
            w1r[2 * k] = t.x; w1r[2 * k + 1] = t.y;
        }
        const float b1v = b1[0];

        float acc[2][4] = {{0.f,0.f,0.f,0.f},{0.f,0.f,0.f,0.f}};

        for (int h = 0; h < 2; ++h) {
            const int base = k0 + h * 64;
            const int nrh = (1001 - base < 64) ? (1001 - base) : 64;  // kc=7,h=1 -> 41
            if (h) __syncthreads();
            #pragma unroll
            for (int r = 0; r < 2; ++r) {
                const int idx = tid + r * 128;       // 256 = 4 samples x 64 rows
                const int s = idx >> 6, rr = idx & 63;
                if (rr < nrh) {
                    const float2* p = (const float2*)(A69 + ((size_t)(s0 + s) * 1001 + base + rr) * 30);
                    float v = b1v;
                    #pragma unroll
                    for (int k = 0; k < 15; ++k) {
                        float2 q = p[k];
                        v = fmaf(q.x, w1r[2 * k], v);
                        v = fmaf(q.y, w1r[2 * k + 1], v);
                    }
                    a69s[s * 64 + rr] = v;
                }
            }
            __syncthreads();
            for (int k = 0; k < nrh; ++k) {
                const float a0 = a69s[wv * 128 + k];        // wave-uniform broadcast
                const float a1 = a69s[wv * 128 + 64 + k];
                float w2v[4];
                *(float4*)w2v = *(const float4*)(W2 + (size_t)(base + k) * 256 + c0);
                #pragma unroll
                for (int c = 0; c < 4; ++c) {
                    acc[0][c] = fmaf(a0, w2v[c], acc[0][c]);
                    acc[1][c] = fmaf(a1, w2v[c], acc[1][c]);
                }
            }
        }
        #pragma unroll
        for (int s = 0; s < 2; ++s)
            *(float4*)(ws_part + ((size_t)kc * BATCH + s0 + wv * 2 + s) * 256 + c0) = *(float4*)acc[s];
    } else {
        // ================= GNN: one sample, two waves =================
        const int b = blk / 3;
        float* comp = sm;          // [50][SC]
        float* h_s  = sm + 2200;   // [50][SC]

        for (int i = tid; i < 500; i += 128) {
            const int n = i / 10, f4 = i - n * 10;
            const int row = atoms[b * 50 + n];
            *(float4*)(comp + n * SC + f4 * 4) = *(const float4*)(emb + row * 40 + f4 * 4);
        }
        __syncthreads();

        const int rg = tid / 10;          // 0..9 (valid for tid<100)
        const int cg = tid - rg * 10;     // 0..9
        const int n0 = rg * 5, f0 = cg * 4;
        const bool act = (tid < 100);

        // residual (init comp) column partial over own 5 rows x 4 cols
        float res4[4] = {0, 0, 0, 0};
        if (act) {
            #pragma unroll
            for (int k = 0; k < 5; ++k) {
                float cv[4];
                *(float4*)cv = *(float4*)(comp + (n0 + k) * SC + f0);
                #pragma unroll
                for (int c = 0; c < 4; ++c) res4[c] += cv[c];
            }
        }

        const float* Ab = A + (size_t)b * 2500;

        for (int l = 0; l < 3; ++l) {
            const float* wgl = Wg + l * 1600;
            if (act) {
                // ---- m1: h = leaky(comp @ Wg[l] + bg[l]) ----
                float bgv[4];
                *(float4*)bgv = *(const float4*)(bg + l * 40 + f0);
                float acc[5][4];
                #pragma unroll
                for (int k = 0; k < 5; ++k)
                    #pragma unroll
                    for (int c = 0; c < 4; ++c) acc[k][c] = bgv[c];
                #pragma unroll
                for (int j4 = 0; j4 < 10; ++j4) {
                    float cv[5][4];
                    #pragma unroll
                    for (int k = 0; k < 5; ++k)
                        *(float4*)cv[k] = *(float4*)(comp + (n0 + k) * SC + j4 * 4);
                    #pragma unroll
                    for (int u = 0; u < 4; ++u) {
                        float w4[4];
                        *(float4*)w4 = *(const float4*)(wgl + (j4 * 4 + u) * 40 + f0);
                        #pragma unroll
                        for (int k = 0; k < 5; ++k)
                            #pragma unroll
                            for (int c = 0; c < 4; ++c)
                                acc[k][c] = fmaf(cv[k][u], w4[c], acc[k][c]);
                    }
                }
                #pragma unroll
                for (int k = 0; k < 5; ++k) {
                    float hv[4];
                    #pragma unroll
                    for (int c = 0; c < 4; ++c) {
                        const float s = acc[k][c];
                        hv[c] = s > 0.f ? s : 0.01f * s;
                    }
                    *(float4*)(h_s + (n0 + k) * SC + f0) = *(float4*)hv;
                }
            }
            __syncthreads();   // h complete (and all m1 comp reads done)
            if (act) {
                // ---- m2: comp += A @ h ----
                float acc2[5][4];
                #pragma unroll
                for (int k = 0; k < 5; ++k)
                    #pragma unroll
                    for (int c = 0; c < 4; ++c) acc2[k][c] = 0.f;
                #pragma unroll
                for (int m4 = 0; m4 < 12; ++m4) {
                    float af[5][4];
                    #pragma unroll
                    for (int k = 0; k < 5; ++k) {
                        *(float2*)af[k]       = *(const float2*)(Ab + (n0 + k) * 50 + m4 * 4);
                        *(float2*)(af[k] + 2) = *(const float2*)(Ab + (n0 + k) * 50 + m4 * 4 + 2);
                    }
                    #pragma unroll
                    for (int u = 0; u < 4; ++u) {
                        float h4[4];
                        *(float4*)h4 = *(float4*)(h_s + (m4 * 4 + u) * SC + f0);
                        #pragma unroll
                        for (int k = 0; k < 5; ++k)
                            #pragma unroll
                            for (int c = 0; c < 4; ++c)
                                acc2[k][c] = fmaf(af[k][u], h4[c], acc2[k][c]);
                    }
                }
                {   // tail m = 48, 49
                    float h48[4], h49[4];
                    *(float4*)h48 = *(float4*)(h_s + 48 * SC + f0);
                    *(float4*)h49 = *(float4*)(h_s + 49 * SC + f0);
                    #pragma unroll
                    for (int k = 0; k < 5; ++k) {
                        const float a48 = Ab[(n0 + k) * 50 + 48];
                        const float a49 = Ab[(n0 + k) * 50 + 49];
                        #pragma unroll
                        for (int c = 0; c < 4; ++c) {
                            acc2[k][c] = fmaf(a48, h48[c], acc2[k][c]);
                            acc2[k][c] = fmaf(a49, h49[c], acc2[k][c]);
                        }
                    }
                }
                #pragma unroll
                for (int k = 0; k < 5; ++k) {
                    float cv[4];
                    *(float4*)cv = *(float4*)(comp + (n0 + k) * SC + f0);
                    #pragma unroll
                    for (int c = 0; c < 4; ++c) cv[c] += acc2[k][c];
                    *(float4*)(comp + (n0 + k) * SC + f0) = *(float4*)cv;
                }
            }
            __syncthreads();   // comp update complete before next m1 / final sum
        }

        // mean over atoms + residual: partials [10][40] into h_s, then reduce
        if (act) {
            float s4[4];
            #pragma unroll
            for (int c = 0; c < 4; ++c) s4[c] = res4[c];
            #pragma unroll
            for (int k = 0; k < 5; ++k) {
                float cv[4];
                *(float4*)cv = *(float4*)(comp + (n0 + k) * SC + f0);
                #pragma unroll
                for (int c = 0; c < 4; ++c) s4[c] += cv[c];
            }
            *(float4*)(h_s + rg * 40 + f0) = *(float4*)s4;
        }
        __syncthreads();
        if (tid < 40) {
            float s = 0.f;
            #pragma unroll
            for (int r = 0; r < 10; ++r) s += h_s[r * 40 + tid];
            ws_cv[(size_t)b * 40 + tid] = s * 0.02f;
        }
    }
}

// ===================== k_tail (round-8, unchanged) =====================
__global__ __launch_bounds__(256) void k_tail(
    const float* __restrict__ protein, const float* __restrict__ b2,
    const float* __restrict__ W3, const float* __restrict__ b3,
    const float* __restrict__ Wp, const float* __restrict__ bp,
    const float* __restrict__ Watt, const float* __restrict__ batt,
    const float* __restrict__ Wm, const float* __restrict__ bm,
    const float* __restrict__ Wo, const float* __restrict__ bo,
    const float* __restrict__ ws_cv, const float* __restrict__ ws_part,
    float* __restrict__ out)
{
    const int G = 8, PC = 520;
    __shared__ float pc[8 * 520];
    __shared__ float p40s[8 * 40];
    __shared__ float phs[8 * 40];
    __shared__ float wts[8];
    __shared__ float cps[2][8 * 84];
    const int tid  = threadIdx.x;
    const int lane = tid & 63, wv = tid >> 6;
    const int b0   = blockIdx.x * G;
    const int c0   = lane * 4;

    if (wv < 2) {
        float acc[4][4];
        #pragma unroll
        for (int s = 0; s < 4; ++s)
            #pragma unroll
            for (int c = 0; c < 4; ++c) acc[s][c] = 0.f;
        const float* prot = protein + (size_t)(b0 + wv * 4) * 512;
        for (int j4 = 0; j4 < 128; ++j4) {
            float pv[4][4];
            #pragma unroll
            for (int s = 0; s < 4; ++s)
                *(float4*)pv[s] = *(const float4*)(prot + (size_t)s * 512 + j4 * 4);
            #pragma unroll
            for (int u = 0; u < 4; ++u) {
                float w3v[4];
                *(float4*)w3v = *(const float4*)(W3 + (size_t)(j4 * 4 + u) * 256 + c0);
                #pragma unroll
                for (int s = 0; s < 4; ++s)
                    #pragma unroll
                    for (int c = 0; c < 4; ++c)
                        acc[s][c] = fmaf(pv[s][u], w3v[c], acc[s][c]);
            }
        }
        float b3v[4];
        *(float4*)b3v = *(const float4*)(b3 + c0);
        #pragma unroll
        for (int s = 0; s < 4; ++s) {
            float o[4];
            #pragma unroll
            for (int c = 0; c < 4; ++c) o[c] = acc[s][c] + b3v[c];
            *(float4*)(pc + (wv * 4 + s) * PC + 256 + c0) = *(float4*)o;
        }
    } else {
        const int sbase = (wv - 2) * 4;
        float b2v[4];
        *(float4*)b2v = *(const float4*)(b2 + c0);
        #pragma unroll
        for (int s = 0; s < 4; ++s) {
            float o[4] = {b2v[0], b2v[1], b2v[2], b2v[3]};
            #pragma unroll
            for (int kc = 0; kc < 8; ++kc) {
                float pv[4];
                *(float4*)pv = *(const float4*)(ws_part + ((size_t)kc * BATCH + b0 + sbase + s) * 256 + c0);
                #pragma unroll
                for (int c = 0; c < 4; ++c) o[c] += pv[c];
            }
            *(float4*)(pc + (sbase + s) * PC + c0) = *(float4*)o;
        }
    }
    __syncthreads();

    if (tid < 40) {
        const int f8 = tid >> 3, g = tid & 7, fo = f8 * 8;
        float a8[8];
        #pragma unroll
        for (int c = 0; c < 8; ++c) a8[c] = bp[fo + c];
        for (int j4 = 0; j4 < 128; ++j4) {
            float pv[4];
            *(float4*)pv = *(float4*)(pc + g * PC + j4 * 4);
            #pragma unroll
            for (int u = 0; u < 4; ++u) {
                const int j = j4 * 4 + u;
                float wa[4], wb[4];
                *(float4*)wa = *(const float4*)(Wp + j * 40 + fo);
                *(float4*)wb = *(const float4*)(Wp + j * 40 + fo + 4);
                #pragma unroll
                for (int c = 0; c < 4; ++c) {
                    a8[c]     = fmaf(pv[u], wa[c], a8[c]);
                    a8[4 + c] = fmaf(pv[u], wb[c], a8[4 + c]);
                }
            }
        }
        *(float4*)(p40s + g * 40 + fo)     = *(float4*)a8;
        *(float4*)(p40s + g * 40 + fo + 4) = *(float4*)(a8 + 4);
    }
    __syncthreads();

    for (int it = tid; it < G * 40; it += 256) {
        const int g = it / 40, f = it - g * 40;
        float s = batt[f];
        #pragma unroll
        for (int j4 = 0; j4 < 10; ++j4) {
            float pv[4];
            *(float4*)pv = *(float4*)(p40s + g * 40 + j4 * 4);
            #pragma unroll
            for (int u = 0; u < 4; ++u)
                s = fmaf(pv[u], Watt[(j4 * 4 + u) * 40 + f], s);
        }
        phs[it] = s > 0.f ? s : 0.f;
    }
    __syncthreads();

    if (tid < G) {
        float m = 0.f;
        #pragma unroll
        for (int f4 = 0; f4 < 10; ++f4) {
            float cv[4], ph[4];
            *(float4*)cv = *(const float4*)(ws_cv + (size_t)(b0 + tid) * 40 + f4 * 4);
            *(float4*)ph = *(float4*)(phs + tid * 40 + f4 * 4);
            #pragma unroll
            for (int c = 0; c < 4; ++c) m = fmaf(cv[c], ph[c], m);
        }
        wts[tid] = tanhf(m);
    }
    __syncthreads();

    for (int it = tid; it < G * 80; it += 256) {
        const int g = it / 80, f = it - g * 80;
        const float v = (f < 40) ? ws_cv[(size_t)(b0 + g) * 40 + f]
                                 : wts[g] * phs[g * 40 + (f - 40)];
        cps[0][g * 84 + f] = v;
    }
    __syncthreads();

    int cb = 0;
    for (int l = 0; l < 2; ++l) {
        for (int it = tid; it < G * 80; it += 256) {
            const int g = it / 80, kk = it - g * 80;
            float s = bm[l * 80 + kk];
            #pragma unroll
            for (int j4 = 0; j4 < 20; ++j4) {
                float cv[4];
                *(float4*)cv = *(float4*)(cps[cb] + g * 84 + j4 * 4);
                #pragma unroll
                for (int u = 0; u < 4; ++u)
                    s = fmaf(cv[u], Wm[l * 6400 + (j4 * 4 + u) * 80 + kk], s);
            }
            cps[cb ^ 1][g * 84 + kk] = s > 0.f ? s : 0.f;
        }
        __syncthreads();
        cb ^= 1;
    }
    if (tid < G) {
        float s = bo[0];
        #pragma unroll
        for (int j4 = 0; j4 < 20; ++j4) {
            float cv[4], wo[4];
            *(float4*)cv = *(float4*)(cps[cb] + tid * 84 + j4 * 4);
            *(float4*)wo = *(const float4*)(Wo + j4 * 4);
            #pragma unroll
            for (int u = 0; u < 4; ++u) s = fmaf(cv[u], wo[u], s);
        }
        out[b0 + tid] = s;
    }
}

extern "C" void kernel_launch(void* const* d_in, const int* in_sizes, int n_in,
                              void* d_out, int out_size, void* d_ws, size_t ws_size,
                              hipStream_t stream) {
    const int*   atoms   = (const int*)d_in[0];
    const float* A       = (const float*)d_in[1];
    const float* A69     = (const float*)d_in[2];
    const float* protein = (const float*)d_in[3];
    const float* emb     = (const float*)d_in[4];
    const float* Wg      = (const float*)d_in[5];
    const float* bg      = (const float*)d_in[6];
    const float* Watt    = (const float*)d_in[7];
    const float* batt    = (const float*)d_in[8];
    const float* W1      = (const float*)d_in[9];
    const float* b1      = (const float*)d_in[10];
    const float* W2      = (const float*)d_in[11];
    const float* b2      = (const float*)d_in[12];
    const float* W3      = (const float*)d_in[13];
    const float* b3      = (const float*)d_in[14];
    const float* Wp      = (const float*)d_in[15];
    const float* bp      = (const float*)d_in[16];
    const float* Wm      = (const float*)d_in[17];
    const float* bm      = (const float*)d_in[18];
    const float* Wo      = (const float*)d_in[19];
    const float* bo      = (const float*)d_in[20];

    float* ws_cv   = (float*)d_ws;                  // [4096][40]
    float* ws_part = ws_cv + (size_t)BATCH * 40;    // [8][4096][256]
    float* outp    = (float*)d_out;

    k_main<<<dim3(12288), dim3(128), 0, stream>>>(
        atoms, A, A69, emb, Wg, bg, W1, b1, W2, ws_cv, ws_part);
    k_tail<<<dim3(512), dim3(256), 0, stream>>>(
        protein, b2, W3, b3, Wp, bp, Watt, batt, Wm, bm, Wo, bo,
        ws_cv, ws_part, outp);
}